// Round 2
// baseline (310.809 us; speedup 1.0000x reference)
//
#include <hip/hip_runtime.h>

#define EPS 1e-10f

// 16 lanes per ray, 4 rays per wave, 8 samples per lane (N=128).
// All global loads are dwordx4; scan/reduce are width-16 shuffles.
__global__ __launch_bounds__(256) void vr_kernel(
    const float* __restrict__ alpha,   // [R,128]
    const float* __restrict__ rgbs,    // [R,128,3]
    float* __restrict__ out,           // [R,3]
    int R)
{
    const int tid = blockIdx.x * blockDim.x + threadIdx.x;
    const int ray = tid >> 4;          // 16 lanes per ray
    const int sub = tid & 15;          // position within ray's lane group
    if (ray >= R) return;

    const float* a = alpha + (size_t)ray * 128 + sub * 8;
    const float* c = rgbs  + (size_t)ray * 384 + sub * 24;

    // alpha: 8 consecutive samples, two float4 loads
    const float4 a0 = *(const float4*)(a);
    const float4 a1 = *(const float4*)(a + 4);

    const float C = 1.0f + EPS;
    const float t0 = C - a0.x, t1 = C - a0.y, t2 = C - a0.z, t3 = C - a0.w;
    const float t4 = C - a1.x, t5 = C - a1.y, t6 = C - a1.z, t7 = C - a1.w;

    // product of this lane's 8 transmittance factors (balanced tree)
    const float local = ((t0 * t1) * (t2 * t3)) * ((t4 * t5) * (t6 * t7));

    // width-16 inclusive product scan across the ray's 16 lanes
    float scan = local;
    #pragma unroll
    for (int off = 1; off < 16; off <<= 1) {
        float v = __shfl_up(scan, off, 16);
        if (sub >= off) scan *= v;
    }
    // exclusive prefix (product of lanes < sub), exact
    float excl = __shfl_up(scan, 1, 16);
    if (sub == 0) excl = 1.0f;

    // per-sample transmittance (exclusive cumprod with shift=1) and weights
    const float T0 = excl;
    const float T1 = T0 * t0;
    const float T2 = T1 * t1;
    const float T3 = T2 * t2;
    const float T4 = T3 * t3;
    const float T5 = T4 * t4;
    const float T6 = T5 * t5;
    const float T7 = T6 * t6;

    const float w0 = T0 * a0.x, w1 = T1 * a0.y, w2 = T2 * a0.z, w3 = T3 * a0.w;
    const float w4 = T4 * a1.x, w5 = T5 * a1.y, w6 = T6 * a1.z, w7 = T7 * a1.w;

    // rgb: 24 consecutive floats = 6 float4 loads
    const float4* cp = (const float4*)c;
    const float4 c0 = cp[0];  // r0 g0 b0 r1
    const float4 c1 = cp[1];  // g1 b1 r2 g2
    const float4 c2 = cp[2];  // b2 r3 g3 b3
    const float4 c3 = cp[3];  // r4 g4 b4 r5
    const float4 c4 = cp[4];  // g5 b5 r6 g6
    const float4 c5 = cp[5];  // b6 r7 g7 b7

    float sr = w0*c0.x + w1*c0.w + w2*c1.z + w3*c2.y + w4*c3.x + w5*c3.w + w6*c4.z + w7*c5.y;
    float sg = w0*c0.y + w1*c1.x + w2*c1.w + w3*c2.z + w4*c3.y + w5*c4.x + w6*c4.w + w7*c5.z;
    float sb = w0*c0.z + w1*c1.y + w2*c2.x + w3*c2.w + w4*c3.z + w5*c4.y + w6*c5.x + w7*c5.w;

    // width-16 butterfly reduction (valid in all lanes; sub 0 writes)
    #pragma unroll
    for (int m = 1; m < 16; m <<= 1) {
        sr += __shfl_xor(sr, m, 16);
        sg += __shfl_xor(sg, m, 16);
        sb += __shfl_xor(sb, m, 16);
    }

    if (sub == 0) {
        float* o = out + (size_t)ray * 3;
        o[0] = sr;
        o[1] = sg;
        o[2] = sb;
    }
}

extern "C" void kernel_launch(void* const* d_in, const int* in_sizes, int n_in,
                              void* d_out, int out_size, void* d_ws, size_t ws_size,
                              hipStream_t stream) {
    const float* alpha = (const float*)d_in[0];
    const float* rgbs  = (const float*)d_in[1];
    float* out = (float*)d_out;

    const int R = in_sizes[0] / 128;            // 131072 rays
    const int rays_per_block = 256 / 16;        // 16 rays per 256-thread block
    const int grid = (R + rays_per_block - 1) / rays_per_block;

    vr_kernel<<<grid, 256, 0, stream>>>(alpha, rgbs, out, R);
}